// Round 2
// baseline (442.662 us; speedup 1.0000x reference)
//
#include <hip/hip_runtime.h>
#include <hip/hip_bf16.h>

typedef __attribute__((ext_vector_type(8))) short short8;
typedef __attribute__((ext_vector_type(8))) __bf16 bf16x8;
typedef __attribute__((ext_vector_type(4))) float f32x4;

#define N_   4096
#define CQD  128
#define PLD  136   // 128 + 8 pad (272B row stride)

static __device__ __forceinline__ unsigned short f2bf(float f) {
    union { float f; unsigned int u; } cv; cv.f = f;
    unsigned int u = cv.u;
    u += 0x7fffu + ((u >> 16) & 1u);   // RNE
    return (unsigned short)(u >> 16);
}

static __device__ __forceinline__ f32x4 mfma16(bf16x8 a, bf16x8 b, f32x4 c) {
    return __builtin_amdgcn_mfma_f32_16x16x32_bf16(a, b, c, 0, 0, 0);
}

// ---------------------------------------------------------------------------
// proj: x2d (B,64,N,16) -> Qb[b][n][c'], Kb[b][m][c'] (c' contig),
//       PV[b][c'][m] (m contig).  Linear col mapping: col = n*16+dd.
// grid 512 (2 batches x 256 col-tiles of 256), block 256.
// Reads: lane-contiguous 4B (perfect). PV stores: LDS transpose -> 32B rows.
// ---------------------------------------------------------------------------
__global__ __launch_bounds__(256) void proj_kernel(
    const float* __restrict__ x2d,
    const float* __restrict__ Wq, const float* __restrict__ bq,
    const float* __restrict__ Wk, const float* __restrict__ bk,
    const float* __restrict__ Wv, const float* __restrict__ bv,
    unsigned short* __restrict__ Qb, unsigned short* __restrict__ Kb,
    unsigned short* __restrict__ PV)
{
    __shared__ unsigned short vlds[64][16][24];  // [j][dd][n], dd-stride 48B (16B-aligned)

    const int t    = threadIdx.x;
    const int blk  = blockIdx.x;        // 0..511
    const int b    = blk >> 8;
    const int nblk = blk & 255;
    const int col  = (nblk << 8) + t;   // 0..65535 within batch
    const int n    = col >> 4;
    const int dd   = col & 15;
    const int nl   = n & 15;

    const float* xb = x2d + (size_t)b * 64 * 65536 + col;
    float xr[64];
#pragma unroll
    for (int c = 0; c < 64; ++c) xr[c] = xb[(size_t)c * 65536];

    // Q/K rows
    unsigned short* qb = Qb + (size_t)b * N_ * CQD + (size_t)n * CQD + dd;
    unsigned short* kb = Kb + (size_t)b * N_ * CQD + (size_t)n * CQD + dd;
#pragma unroll 2
    for (int j = 0; j < 8; ++j) {
        float aq = bq[j], ak = bk[j];
#pragma unroll
        for (int c = 0; c < 64; ++c) {
            float xv = xr[c];
            aq += Wq[j * 64 + c] * xv;
            ak += Wk[j * 64 + c] * xv;
        }
        qb[j * 16] = f2bf(aq);
        kb[j * 16] = f2bf(ak);
    }

    // V rows -> LDS transpose buffer
#pragma unroll 4
    for (int j = 0; j < 64; ++j) {
        float acc = bv[j];
#pragma unroll
        for (int c = 0; c < 64; ++c) acc += Wv[j * 64 + c] * xr[c];
        vlds[j][dd][nl] = f2bf(acc);
    }
    __syncthreads();

    // write-out: rows r = c' = j*16+dd; 16 n values (32B) per row per block
    unsigned short* pvb = PV + (size_t)b * 1024 * N_ + (size_t)(nblk << 4);
#pragma unroll
    for (int rr = 0; rr < 4; ++rr) {
        const int r = (rr << 8) + t;
        const short8 v0 = *reinterpret_cast<const short8*>(&vlds[r >> 4][r & 15][0]);
        const short8 v1 = *reinterpret_cast<const short8*>(&vlds[r >> 4][r & 15][8]);
        *reinterpret_cast<short8*>(pvb + (size_t)r * N_)     = v0;
        *reinterpret_cast<short8*>(pvb + (size_t)r * N_ + 8) = v1;
    }
}

// ---------------------------------------------------------------------------
// attn: 512 blocks = (batch x c-quarter 256) [XCD-pinned via id&7] x 64 n-tiles.
// 8 waves/512 thr, 2 blocks/CU. Per m-step 128: waves build p = exp(QK^T)
// (64x128) in dbuf LDS, then GEMM p @ PV c-slice (32c per wave).
// Unnormalized accumulation + rowsum; divide + gamma*O + x3d epilogue.
// ---------------------------------------------------------------------------
__global__ __launch_bounds__(512, 4) void attn_kernel(
    const unsigned short* __restrict__ Qb, const unsigned short* __restrict__ Kb,
    const unsigned short* __restrict__ PV,
    const float* __restrict__ x3d, const float* __restrict__ gamma_p,
    float* __restrict__ outp)
{
    __shared__ unsigned short p_lds[2][64][PLD];
    __shared__ float red[64];

    const int t  = threadIdx.x;
    const int w  = t >> 6;
    const int l  = t & 63;
    const int lo = l & 15;
    const int hi = l >> 4;

    const int id    = blockIdx.x;        // 0..511
    const int combo = id & 7;            // XCD = id % 8 (dispatch heuristic)
    const int ntile = id >> 3;
    const int b     = combo >> 2;
    const int cq    = combo & 3;
    const int n0    = ntile << 6;
    const int cw    = (cq << 8) + (w << 5);   // wave's 32-wide c' base
    const int g     = w >> 2;                 // E row group (32 rows)
    const int msel  = w & 3;                  // E 32-wide m-subchunk

    const unsigned short* qp  = Qb + (size_t)b * N_ * CQD;
    const unsigned short* kp  = Kb + (size_t)b * N_ * CQD;
    const unsigned short* pvp = PV + (size_t)b * 1024 * N_;

    // Q A-frags for this wave's E rows (32 VGPRs)
    bf16x8 qf[2][4];
#pragma unroll
    for (int ns = 0; ns < 2; ++ns)
#pragma unroll
        for (int kk = 0; kk < 4; ++kk)
            qf[ns][kk] = *reinterpret_cast<const bf16x8*>(
                qp + (size_t)(n0 + g * 32 + ns * 16 + lo) * CQD + kk * 32 + hi * 8);

    f32x4 acc[4][2];
#pragma unroll
    for (int i = 0; i < 4; ++i)
#pragma unroll
        for (int j = 0; j < 2; ++j) acc[i][j] = (f32x4){0.f, 0.f, 0.f, 0.f};
    float rs[8];
#pragma unroll
    for (int i = 0; i < 8; ++i) rs[i] = 0.f;

    if (t < 64) red[t] = 0.f;

    for (int it = 0; it < 32; ++it) {
        const int m0  = it << 7;
        const int buf = it & 1;
        const int mc  = m0 + (msel << 5);

        // ---- E phase: 32n x 32m chunk, per-16m to limit live regs ----
#pragma unroll
        for (int ms = 0; ms < 2; ++ms) {
            bf16x8 kf[4];
#pragma unroll
            for (int kk = 0; kk < 4; ++kk)
                kf[kk] = *reinterpret_cast<const bf16x8*>(
                    kp + (size_t)(mc + ms * 16 + lo) * CQD + kk * 32 + hi * 8);
            f32x4 e0 = (f32x4){0.f, 0.f, 0.f, 0.f};
            f32x4 e1 = (f32x4){0.f, 0.f, 0.f, 0.f};
#pragma unroll
            for (int kk = 0; kk < 4; ++kk) {
                e0 = mfma16(qf[0][kk], kf[kk], e0);
                e1 = mfma16(qf[1][kk], kf[kk], e1);
            }
#pragma unroll
            for (int r = 0; r < 4; ++r) {
                float p0 = __expf(e0[r]);
                float p1 = __expf(e1[r]);
                rs[r]     += p0;
                rs[4 + r] += p1;
                p_lds[buf][g * 32 + hi * 4 + r][(msel << 5) + ms * 16 + lo]      = f2bf(p0);
                p_lds[buf][g * 32 + 16 + hi * 4 + r][(msel << 5) + ms * 16 + lo] = f2bf(p1);
            }
        }
        __syncthreads();   // one barrier/iter; dbuf covers write-after-read

        // ---- PV phase: p (64x128) @ PV^T (128 x 32c slice) ----
#pragma unroll
        for (int kk = 0; kk < 4; ++kk) {
            bf16x8 af[4];
#pragma unroll
            for (int ns = 0; ns < 4; ++ns)
                af[ns] = *reinterpret_cast<const bf16x8*>(&p_lds[buf][ns * 16 + lo][kk * 32 + hi * 8]);
            bf16x8 bvv[2];
#pragma unroll
            for (int cs = 0; cs < 2; ++cs)
                bvv[cs] = *reinterpret_cast<const bf16x8*>(
                    pvp + (size_t)(cw + cs * 16 + lo) * N_ + m0 + kk * 32 + hi * 8);
#pragma unroll
            for (int ns = 0; ns < 4; ++ns)
#pragma unroll
                for (int cs = 0; cs < 2; ++cs)
                    acc[ns][cs] = mfma16(af[ns], bvv[cs], acc[ns][cs]);
        }
    }

    // ---- rowsum: reduce over lo-lanes (m columns), accumulate across waves ----
#pragma unroll
    for (int i = 0; i < 8; ++i) {
        float v = rs[i];
        v += __shfl_xor(v, 1);
        v += __shfl_xor(v, 2);
        v += __shfl_xor(v, 4);
        v += __shfl_xor(v, 8);
        rs[i] = v;
    }
    if (lo == 0) {
#pragma unroll
        for (int ns = 0; ns < 2; ++ns)
#pragma unroll
            for (int r = 0; r < 4; ++r)
                atomicAdd(&red[g * 32 + ns * 16 + hi * 4 + r], rs[ns * 4 + r]);
    }
    __syncthreads();

    // ---- epilogue: out = gamma * O / rowsum + x3d ----
    const float gmv = gamma_p[0];
    const float* x3p = x3d + (size_t)b * 64 * N_ * 16;
    float* op        = outp + (size_t)b * 64 * N_ * 16;
#pragma unroll
    for (int ns = 0; ns < 4; ++ns) {
        float rinv[4];
#pragma unroll
        for (int r = 0; r < 4; ++r) rinv[r] = 1.0f / red[ns * 16 + hi * 4 + r];
#pragma unroll
        for (int cs = 0; cs < 2; ++cs) {
            const int cp = cw + cs * 16 + lo;
            const size_t base = (size_t)(cp >> 4) * (N_ * 16) + (size_t)(cp & 15);
#pragma unroll
            for (int r = 0; r < 4; ++r) {
                const size_t idx = base + (size_t)(n0 + ns * 16 + hi * 4 + r) * 16;
                op[idx] = gmv * acc[ns][cs][r] * rinv[r] + x3p[idx];
            }
        }
    }
}

extern "C" void kernel_launch(void* const* d_in, const int* in_sizes, int n_in,
                              void* d_out, int out_size, void* d_ws, size_t ws_size,
                              hipStream_t stream)
{
    const float* x2d = (const float*)d_in[0];
    const float* x3d = (const float*)d_in[1];
    const float* Wq  = (const float*)d_in[2];
    const float* bq  = (const float*)d_in[3];
    const float* Wk  = (const float*)d_in[4];
    const float* bk  = (const float*)d_in[5];
    const float* Wv  = (const float*)d_in[6];
    const float* bv  = (const float*)d_in[7];
    const float* gm  = (const float*)d_in[8];

    char* ws = (char*)d_ws;
    unsigned short* Qb = (unsigned short*)ws;                    // 2 MiB
    unsigned short* Kb = (unsigned short*)(ws + (2u << 20));     // 2 MiB
    unsigned short* PV = (unsigned short*)(ws + (4u << 20));     // 16 MiB

    proj_kernel<<<512, 256, 0, stream>>>(x2d, Wq, bq, Wk, bk, Wv, bv, Qb, Kb, PV);
    attn_kernel<<<512, 512, 0, stream>>>(Qb, Kb, PV, x3d, gm, (float*)d_out);
}

// Round 3
// 334.806 us; speedup vs baseline: 1.3221x; 1.3221x over previous
//
#include <hip/hip_runtime.h>
#include <hip/hip_bf16.h>

typedef __attribute__((ext_vector_type(8))) short short8;
typedef __attribute__((ext_vector_type(8))) __bf16 bf16x8;
typedef __attribute__((ext_vector_type(4))) float f32x4;

#define N_   4096
#define CQD  128

static __device__ __forceinline__ unsigned short f2bf(float f) {
    union { float f; unsigned int u; } cv; cv.f = f;
    unsigned int u = cv.u;
    u += 0x7fffu + ((u >> 16) & 1u);   // RNE
    return (unsigned short)(u >> 16);
}

static __device__ __forceinline__ f32x4 mfma16(bf16x8 a, bf16x8 b, f32x4 c) {
    return __builtin_amdgcn_mfma_f32_16x16x32_bf16(a, b, c, 0, 0, 0);
}

// ---------------------------------------------------------------------------
// proj: x2d (B,64,N*16) -> Qb[n][c'], Kb[m][c'] (c' contig), PV[c'][m] (m contig)
// grid 1024 = 2 b x 512 col-tiles (128 cols); block 512 = 4 row-groups x 128 cols.
// Stage x-tile (64x128 f32, 32 KB LDS) once; rows split: jg0 = q8+k8,
// jg1..3 = v rows 22/22/20. V bounced through 16 KB LDS (union) -> 16B stores.
// ---------------------------------------------------------------------------
__global__ __launch_bounds__(512) void proj_kernel(
    const float* __restrict__ x2d,
    const float* __restrict__ Wq, const float* __restrict__ bq,
    const float* __restrict__ Wk, const float* __restrict__ bk,
    const float* __restrict__ Wv, const float* __restrict__ bv,
    unsigned short* __restrict__ Qb, unsigned short* __restrict__ Kb,
    unsigned short* __restrict__ PV)
{
    __shared__ char smem[32768];
    float*          xlds = (float*)smem;            // [64][128]
    unsigned short* vout = (unsigned short*)smem;   // [1024 rows][8 n] (16 KB)

    const int t    = threadIdx.x;
    const int blk  = blockIdx.x;            // 0..1023
    const int b    = blk >> 9;
    const int tile = blk & 511;
    const int col0 = tile << 7;
    const int jg   = __builtin_amdgcn_readfirstlane(t >> 7);  // wave-uniform
    const int tl   = t & 127;
    const int dd   = tl & 15;
    const int nl   = tl >> 4;               // 0..7
    const int col  = col0 + tl;
    const int n    = col >> 4;

    // ---- stage x tile: 64 rows x 128 cols ----
    const float* xb = x2d + (size_t)b * 64 * 65536 + col0;
#pragma unroll
    for (int i = 0; i < 16; ++i) {
        const int idx = (i << 9) + t;
        xlds[idx] = xb[(size_t)(idx >> 7) * 65536 + (idx & 127)];
    }
    __syncthreads();

    if (jg == 0) {
        // ---- q (8 rows) + k (8 rows) ----
        float aq[8], ak[8];
#pragma unroll
        for (int j = 0; j < 8; ++j) { aq[j] = bq[j]; ak[j] = bk[j]; }
#pragma unroll 16
        for (int c = 0; c < 64; ++c) {
            const float xv = xlds[c * 128 + tl];
#pragma unroll
            for (int j = 0; j < 8; ++j) {
                aq[j] += Wq[j * 64 + c] * xv;
                ak[j] += Wk[j * 64 + c] * xv;
            }
        }
        unsigned short* qb = Qb + (size_t)b * N_ * CQD + (size_t)n * CQD + dd;
        unsigned short* kb = Kb + (size_t)b * N_ * CQD + (size_t)n * CQD + dd;
#pragma unroll
        for (int j = 0; j < 8; ++j) {
            qb[j * 16] = f2bf(aq[j]);
            kb[j * 16] = f2bf(ak[j]);
        }
        __syncthreads();   // all xlds reads done
        __syncthreads();   // vout written by jg1..3
    } else {
        // ---- v rows v0 .. v0+21 (clamped) ----
        const int v0 = (jg - 1) * 22;
        int wr[22];
#pragma unroll
        for (int j = 0; j < 22; ++j) wr[j] = (v0 + j < 64) ? (v0 + j) : 63;
        float av[22];
#pragma unroll
        for (int j = 0; j < 22; ++j) av[j] = bv[wr[j]];
#pragma unroll 16
        for (int c = 0; c < 64; ++c) {
            const float xv = xlds[c * 128 + tl];
#pragma unroll
            for (int j = 0; j < 22; ++j) av[j] += Wv[wr[j] * 64 + c] * xv;
        }
        __syncthreads();   // all xlds reads done -> safe to overwrite as vout
#pragma unroll
        for (int j = 0; j < 22; ++j) {
            if (v0 + j < 64)
                vout[(size_t)(((v0 + j) << 4) + dd) * 8 + nl] = f2bf(av[j]);
        }
        __syncthreads();
    }

    // ---- writeout: 1024 PV rows x 8 m, 16B per row ----
    unsigned short* pvb = PV + (size_t)b * 1024 * N_ + (tile << 3);
#pragma unroll
    for (int i = 0; i < 2; ++i) {
        const int r = t + (i << 9);
        const short8 v = *reinterpret_cast<const short8*>(vout + r * 8);
        *reinterpret_cast<short8*>(pvb + (size_t)r * N_) = v;
    }
}

// ---------------------------------------------------------------------------
// attn: 256 blocks = (b x c-half) [2 XCDs each via id bits] x 64 n-tiles.
// Per iter: issue kf loads, then all 16 bvv loads (stay in flight across E +
// barrier, FIFO vmcnt) -> E (16 MFMA) -> exp -> swizzled p write -> barrier ->
// PV (64 MFMA, zero L2 stalls). p_lds XOR-swizzled: byte ^= (row&15)<<4.
// ---------------------------------------------------------------------------
__global__ __launch_bounds__(512, 2) void attn_kernel(
    const unsigned short* __restrict__ Qb, const unsigned short* __restrict__ Kb,
    const unsigned short* __restrict__ PV,
    const float* __restrict__ x3d, const float* __restrict__ gamma_p,
    float* __restrict__ outp)
{
    __shared__ char pbuf[2][64 * 256];   // [64 rows][128 m] bf16, swizzled
    __shared__ float red[64];

    const int t  = threadIdx.x;
    const int w  = t >> 6;
    const int l  = t & 63;
    const int lo = l & 15;
    const int hi = l >> 4;

    const int id    = blockIdx.x;              // 0..255
    const int combo = (id >> 1) & 3;           // (b, c-half) -> 2 XCDs each
    const int chalf = combo & 1;
    const int b     = combo >> 1;
    const int xl    = ((id >> 3) << 1) | (id & 1);
    const int n0    = xl << 6;
    const int cw    = (chalf << 9) + (w << 6); // wave's 64-wide c' base
    const int g     = w >> 2;                  // E row group
    const int msel  = w & 3;                   // E m-subchunk

    const unsigned short* qp  = Qb + (size_t)b * N_ * CQD;
    const unsigned short* kp  = Kb + (size_t)b * N_ * CQD;
    const unsigned short* pvp = PV + (size_t)b * 1024 * N_;

    bf16x8 qf[2][4];
#pragma unroll
    for (int ns = 0; ns < 2; ++ns)
#pragma unroll
        for (int kk = 0; kk < 4; ++kk)
            qf[ns][kk] = *reinterpret_cast<const bf16x8*>(
                qp + (size_t)(n0 + g * 32 + ns * 16 + lo) * CQD + kk * 32 + hi * 8);

    f32x4 acc[4][4];
#pragma unroll
    for (int i = 0; i < 4; ++i)
#pragma unroll
        for (int j = 0; j < 4; ++j) acc[i][j] = (f32x4){0.f, 0.f, 0.f, 0.f};
    float rs[8];
#pragma unroll
    for (int i = 0; i < 8; ++i) rs[i] = 0.f;

    if (t < 64) red[t] = 0.f;

    for (int it = 0; it < 32; ++it) {
        const int m0  = it << 7;
        const int buf = it & 1;
        const int mc  = m0 + (msel << 5);

        // ---- issue kf FIRST (consumed in E), then bvv (consumed in PV) ----
        bf16x8 kf[2][4];
#pragma unroll
        for (int ms = 0; ms < 2; ++ms)
#pragma unroll
            for (int kk = 0; kk < 4; ++kk)
                kf[ms][kk] = *reinterpret_cast<const bf16x8*>(
                    kp + (size_t)(mc + ms * 16 + lo) * CQD + kk * 32 + hi * 8);
        bf16x8 bvv[4][4];
#pragma unroll
        for (int kk = 0; kk < 4; ++kk)
#pragma unroll
            for (int cs = 0; cs < 4; ++cs)
                bvv[kk][cs] = *reinterpret_cast<const bf16x8*>(
                    pvp + (size_t)(cw + cs * 16 + lo) * N_ + m0 + kk * 32 + hi * 8);

        // ---- E phase: 32n x 32m ----
        char* pb = pbuf[buf];
#pragma unroll
        for (int ms = 0; ms < 2; ++ms) {
            f32x4 e0 = (f32x4){0.f, 0.f, 0.f, 0.f};
            f32x4 e1 = (f32x4){0.f, 0.f, 0.f, 0.f};
#pragma unroll
            for (int kk = 0; kk < 4; ++kk) {
                e0 = mfma16(qf[0][kk], kf[ms][kk], e0);
                e1 = mfma16(qf[1][kk], kf[ms][kk], e1);
            }
            const int colb = ((msel << 5) + ms * 16 + lo) * 2;
#pragma unroll
            for (int r = 0; r < 4; ++r) {
                const float p0 = __expf(e0[r]);
                const float p1 = __expf(e1[r]);
                rs[r]     += p0;
                rs[4 + r] += p1;
                const int row0 = g * 32 + hi * 4 + r;
                const int row1 = row0 + 16;
                *(unsigned short*)(pb + row0 * 256 + (colb ^ ((row0 & 15) << 4))) = f2bf(p0);
                *(unsigned short*)(pb + row1 * 256 + (colb ^ ((row1 & 15) << 4))) = f2bf(p1);
            }
        }
        __syncthreads();

        // ---- PV phase: p (64x128) @ PV^T (128 x 64c), bvv already landed ----
#pragma unroll
        for (int kk = 0; kk < 4; ++kk) {
            bf16x8 af[4];
#pragma unroll
            for (int ns = 0; ns < 4; ++ns) {
                const int row = ns * 16 + lo;
                af[ns] = *reinterpret_cast<const bf16x8*>(
                    pb + row * 256 + ((kk * 64 + hi * 16) ^ ((row & 15) << 4)));
            }
#pragma unroll
            for (int ns = 0; ns < 4; ++ns)
#pragma unroll
                for (int cs = 0; cs < 4; ++cs)
                    acc[ns][cs] = mfma16(af[ns], bvv[kk][cs], acc[ns][cs]);
        }
    }

    // ---- rowsum reduction ----
#pragma unroll
    for (int i = 0; i < 8; ++i) {
        float v = rs[i];
        v += __shfl_xor(v, 1);
        v += __shfl_xor(v, 2);
        v += __shfl_xor(v, 4);
        v += __shfl_xor(v, 8);
        rs[i] = v;
    }
    if (lo == 0) {
#pragma unroll
        for (int ns = 0; ns < 2; ++ns)
#pragma unroll
            for (int r = 0; r < 4; ++r)
                atomicAdd(&red[g * 32 + ns * 16 + hi * 4 + r], rs[ns * 4 + r]);
    }
    __syncthreads();

    // ---- epilogue: out = gamma * O / rowsum + x3d ----
    const float gmv = gamma_p[0];
    const float* x3p = x3d + (size_t)b * 64 * N_ * 16;
    float* op        = outp + (size_t)b * 64 * N_ * 16;
#pragma unroll
    for (int ns = 0; ns < 4; ++ns) {
        float rinv[4];
#pragma unroll
        for (int r = 0; r < 4; ++r) rinv[r] = 1.0f / red[ns * 16 + hi * 4 + r];
#pragma unroll
        for (int cs = 0; cs < 4; ++cs) {
            const int cp = cw + cs * 16 + lo;
            const size_t base = (size_t)(cp >> 4) * (N_ * 16) + (size_t)(cp & 15);
#pragma unroll
            for (int r = 0; r < 4; ++r) {
                const size_t idx = base + (size_t)(n0 + ns * 16 + hi * 4 + r) * 16;
                op[idx] = gmv * acc[ns][cs][r] * rinv[r] + x3p[idx];
            }
        }
    }
}

extern "C" void kernel_launch(void* const* d_in, const int* in_sizes, int n_in,
                              void* d_out, int out_size, void* d_ws, size_t ws_size,
                              hipStream_t stream)
{
    const float* x2d = (const float*)d_in[0];
    const float* x3d = (const float*)d_in[1];
    const float* Wq  = (const float*)d_in[2];
    const float* bq  = (const float*)d_in[3];
    const float* Wk  = (const float*)d_in[4];
    const float* bk  = (const float*)d_in[5];
    const float* Wv  = (const float*)d_in[6];
    const float* bv  = (const float*)d_in[7];
    const float* gm  = (const float*)d_in[8];

    char* ws = (char*)d_ws;
    unsigned short* Qb = (unsigned short*)ws;                    // 2 MiB
    unsigned short* Kb = (unsigned short*)(ws + (2u << 20));     // 2 MiB
    unsigned short* PV = (unsigned short*)(ws + (4u << 20));     // 16 MiB

    proj_kernel<<<1024, 512, 0, stream>>>(x2d, Wq, bq, Wk, bk, Wv, bv, Qb, Kb, PV);
    attn_kernel<<<256, 512, 0, stream>>>(Qb, Kb, PV, x3d, gm, (float*)d_out);
}